// Round 2
// baseline (95.985 us; speedup 1.0000x reference)
//
#include <hip/hip_runtime.h>
#include <stdint.h>

// FMoELinearProj:
//   out[t,k,s] = sum_d inp[k*4096+t, d] * Mt[k,s,d] + b2[k,s]     (f32 out)
//   Mt[k,s,d]  = sum_e W[k,e,d] * P[k,e,s]      (bf16, precomputed in ws)
//   b2[k,s]    = sum_e bias[k,e] * P[k,e,s]     (f32, precomputed in ws)
// Shapes: inp [64*4096, 256] f32; W [64,256,256]; bias [64,256];
//         P [64,256,64]; out [4096,64,64] f32.  All experts full (4096 tok).

typedef unsigned int   u32;
typedef unsigned short u16;

typedef short bf16x8 __attribute__((ext_vector_type(8)));   // 8 bf16
typedef float f32x4  __attribute__((ext_vector_type(4)));

__device__ __forceinline__ u16 f2bf(float f) {              // RNE f32->bf16
  u32 u = __float_as_uint(f);
  return (u16)((u + 0x7fffu + ((u >> 16) & 1u)) >> 16);
}

union BF8 { short s[8]; bf16x8 v; };

__device__ __forceinline__ bf16x8 pack8(const float* v) {
  BF8 r;
#pragma unroll
  for (int j = 0; j < 8; ++j) r.s[j] = (short)f2bf(v[j]);
  return r.v;
}

__device__ __forceinline__ void gload_lds16(const void* g, void* l) {
  __builtin_amdgcn_global_load_lds((__attribute__((address_space(1))) void*)g,
                                   (__attribute__((address_space(3))) void*)l,
                                   16, 0, 0);
}

// ---------- k_b2: b2[k][s] = sum_e bias[k][e] * P[k][e][s] ----------
__global__ __launch_bounds__(256) void k_b2(const float* __restrict__ bias,
                                            const float* __restrict__ P,
                                            float* __restrict__ b2) {
  const int k = blockIdx.x;
  const int tid = threadIdx.x, s = tid & 63, eq = tid >> 6;
  const float* Pk = P + (size_t)k * 16384;    // [256][64]
  const float* bk = bias + k * 256;
  float acc = 0.f;
#pragma unroll 4
  for (int i = 0; i < 64; ++i) {
    const int e = eq * 64 + i;
    acc = fmaf(bk[e], Pk[(size_t)e * 64 + s], acc);
  }
  __shared__ float red[4][64];
  red[eq][s] = acc;
  __syncthreads();
  if (eq == 0) b2[k * 64 + s] = red[0][s] + red[1][s] + red[2][s] + red[3][s];
}

// ---------- k_m: Mt[k][s][d] = sum_e bf16(W[k][e][d]) * bf16(P[k][e][s]) ----
// grid (4,64): block covers 64 d-cols; wave w covers 16 d-cols (1 n-frag).
// Strided scalar loads are L2-served (P_k 64KB, W_k 256KB resident).
__global__ __launch_bounds__(256) void k_m(const float* __restrict__ P,
                                           const float* __restrict__ W,
                                           u16* __restrict__ Mt) {
  const int k = blockIdx.y;
  const int d_base = blockIdx.x * 64;
  const int tid = threadIdx.x, lane = tid & 63, w = tid >> 6;
  const float* Pk = P + (size_t)k * 16384;    // [e=256][s=64]
  const float* Wk = W + (size_t)k * 65536;    // [e=256][d=256]
  u16* Mk = Mt + (size_t)k * 16384;           // [s=64][d=256]
  const int d = d_base + w * 16 + (lane & 15);
  f32x4 acc[4] = {};
#pragma unroll
  for (int kk = 0; kk < 8; ++kk) {            // e-chunks of 32
    const int e0 = kk * 32 + (lane >> 4) * 8;
    float vb[8];
#pragma unroll
    for (int j = 0; j < 8; ++j) vb[j] = Wk[(size_t)(e0 + j) * 256 + d];
    bf16x8 b = pack8(vb);
#pragma unroll
    for (int m = 0; m < 4; ++m) {
      const int s = m * 16 + (lane & 15);
      float va[8];
#pragma unroll
      for (int j = 0; j < 8; ++j) va[j] = Pk[(size_t)(e0 + j) * 64 + s];
      bf16x8 a = pack8(va);
      acc[m] = __builtin_amdgcn_mfma_f32_16x16x32_bf16(a, b, acc[m], 0, 0, 0);
    }
  }
#pragma unroll
  for (int m = 0; m < 4; ++m)
#pragma unroll
    for (int j = 0; j < 4; ++j) {
      const int s = m * 16 + (lane >> 4) * 4 + j;
      Mk[(size_t)s * 256 + d] = f2bf(acc[m][j]);
    }
}

// ---------- k_main: out[t][k][s] = inp_row . Mt[k][s][:] + b2[k][s] ----------
// grid (16,64); block = 4 waves; wave owns 64 tokens x 64 s.
// B (Mt_k, 32KB) staged once: gload_lds linear dest + inverse-swz source;
// swizzled ds_read (u ^= s&7 on 16B chunks).  A read direct global->reg.
__global__ __launch_bounds__(256, 2) void k_main(const float* __restrict__ inp,
                                                 const u16* __restrict__ Mt,
                                                 const float* __restrict__ b2,
                                                 float* __restrict__ out) {
  const int tb = blockIdx.x, k = blockIdx.y;
  const int tid = threadIdx.x, lane = tid & 63, w = tid >> 6;
  __shared__ __align__(16) u16 Bl[16384];     // [s=64][d=256] bf16, swizzled
  const u16* Mk = Mt + (size_t)k * 16384;
#pragma unroll
  for (int r = 0; r < 8; ++r) {               // 32 chunk-loads of 1KB/wave
    const int q = r * 256 + tid;              // 16B-chunk id, q in [0,2048)
    const int s = q >> 5, u = q & 31;         // 32 chunks per 512B row
    gload_lds16(Mk + (size_t)s * 256 + ((u ^ (s & 7)) * 8),
                (char*)Bl + r * 4096 + w * 1024);
  }
  const float* Ak = inp + ((size_t)k * 4096 + tb * 256 + w * 64) * 256;
  f32x4 acc[4][4] = {};
  __syncthreads();                            // the only barrier

#pragma unroll
  for (int kk = 0; kk < 8; ++kk) {            // K-chunks of 32
    bf16x8 b[4];
#pragma unroll
    for (int n = 0; n < 4; ++n) {             // s-rows
      const int s = n * 16 + (lane & 15);
      const int u = kk * 4 + (lane >> 4);
      b[n] = *reinterpret_cast<const bf16x8*>(
          (const char*)Bl + s * 512 + ((u ^ (s & 7)) * 16));
    }
#pragma unroll
    for (int m = 0; m < 4; ++m) {             // token rows
      const float* ap = Ak + (size_t)(m * 16 + (lane & 15)) * 256 +
                        kk * 32 + (lane >> 4) * 8;
      float va[8];
      *reinterpret_cast<float4*>(&va[0]) = *reinterpret_cast<const float4*>(ap);
      *reinterpret_cast<float4*>(&va[4]) = *reinterpret_cast<const float4*>(ap + 4);
      bf16x8 a = pack8(va);
#pragma unroll
      for (int n = 0; n < 4; ++n)
        acc[m][n] = __builtin_amdgcn_mfma_f32_16x16x32_bf16(a, b[n], acc[m][n], 0, 0, 0);
    }
  }

  const float* b2k = b2 + k * 64;
  const int T0 = tb * 256 + w * 64;
#pragma unroll
  for (int n = 0; n < 4; ++n) {
    const int s = n * 16 + (lane & 15);
    const float bv = b2k[s];
#pragma unroll
    for (int m = 0; m < 4; ++m)
#pragma unroll
      for (int j = 0; j < 4; ++j) {
        const int t = T0 + m * 16 + (lane >> 4) * 4 + j;
        out[(size_t)t * 4096 + k * 64 + s] = acc[m][n][j] + bv;
      }
  }
}

extern "C" void kernel_launch(void* const* d_in, const int* in_sizes, int n_in,
                              void* d_out, int out_size, void* d_ws, size_t ws_size,
                              hipStream_t stream) {
  const float* inp  = (const float*)d_in[0];
  // d_in[1] = fwd_expert_count (all 4096), d_in[5] = max_tokens: unused
  const float* W    = (const float*)d_in[2];
  const float* bias = (const float*)d_in[3];
  const float* P    = (const float*)d_in[4];   // [64,256,64]

  // ws: Mt bf16 [64][64][256] @0 (2 MB); b2 f32 [64][64] @2MB (16 KB)
  u16*   Mm = (u16*)d_ws;
  float* b2 = (float*)((char*)d_ws + 2097152);
  float* o  = (float*)d_out;

  k_b2  <<<dim3(64),     256, 0, stream>>>(bias, P, b2);
  k_m   <<<dim3(4, 64),  256, 0, stream>>>(P, W, Mm);
  k_main<<<dim3(16, 64), 256, 0, stream>>>(inp, Mm, b2, o);
}

// Round 3
// 95.211 us; speedup vs baseline: 1.0081x; 1.0081x over previous
//
#include <hip/hip_runtime.h>
#include <hip/hip_bf16.h>
#include <stdint.h>

// FMoELinearProj:
//   out[t,k,s] = sum_d inp[k*4096+t, d] * Mt[k,s,d] + b2[k,s]     (f32 out)
//   Mt[k,s,d]  = sum_e W[k,e,d] * P[k,e,s]      (bf16, precomputed in ws)
//   b2[k,s]    = sum_e bias[k,e] * P[k,e,s]     (f32, precomputed in ws)
// Shapes: inp [64*4096, 256] f32; W [64,256,256]; bias [64,256];
//         P [64,256,64]; out [4096,64,64] f32.  All experts full (4096 tok).

typedef unsigned int   u32;
typedef unsigned short u16;

typedef short bf16x8 __attribute__((ext_vector_type(8)));   // 8 bf16
typedef float f32x4  __attribute__((ext_vector_type(4)));

// Native casts -> compiler emits v_cvt_pk_bf16_f32 (RNE, 1 instr / 2 elems).
__device__ __forceinline__ bf16x8 pack8(const float* v) {
  union { __hip_bfloat16 h[8]; bf16x8 v8; } r;
#pragma unroll
  for (int j = 0; j < 8; ++j) r.h[j] = __float2bfloat16(v[j]);
  return r.v8;
}
__device__ __forceinline__ u16 f2bf1(float f) {
  union { __hip_bfloat16 h; u16 u; } r;
  r.h = __float2bfloat16(f);
  return r.u;
}

__device__ __forceinline__ void gload_lds16(const void* g, void* l) {
  __builtin_amdgcn_global_load_lds((__attribute__((address_space(1))) void*)g,
                                   (__attribute__((address_space(3))) void*)l,
                                   16, 0, 0);
}

// ---------- k_b2: b2[k][s] = sum_e bias[k][e] * P[k][e][s] ----------
__global__ __launch_bounds__(256) void k_b2(const float* __restrict__ bias,
                                            const float* __restrict__ P,
                                            float* __restrict__ b2) {
  const int k = blockIdx.x;
  const int tid = threadIdx.x, s = tid & 63, eq = tid >> 6;
  const float* Pk = P + (size_t)k * 16384;    // [256][64]
  const float* bk = bias + k * 256;
  float acc = 0.f;
#pragma unroll 4
  for (int i = 0; i < 64; ++i) {
    const int e = eq * 64 + i;
    acc = fmaf(bk[e], Pk[(size_t)e * 64 + s], acc);
  }
  __shared__ float red[4][64];
  red[eq][s] = acc;
  __syncthreads();
  if (eq == 0) b2[k * 64 + s] = red[0][s] + red[1][s] + red[2][s] + red[3][s];
}

// ---------- k_m: Mt[k][s][d] = sum_e bf16(W[k][e][d]) * bf16(P[k][e][s]) ----
// grid (4,64): block covers 64 d-cols; wave w covers 16 d-cols (1 n-frag).
__global__ __launch_bounds__(256) void k_m(const float* __restrict__ P,
                                           const float* __restrict__ W,
                                           u16* __restrict__ Mt) {
  const int k = blockIdx.y;
  const int d_base = blockIdx.x * 64;
  const int tid = threadIdx.x, lane = tid & 63, w = tid >> 6;
  const float* Pk = P + (size_t)k * 16384;    // [e=256][s=64]
  const float* Wk = W + (size_t)k * 65536;    // [e=256][d=256]
  u16* Mk = Mt + (size_t)k * 16384;           // [s=64][d=256]
  const int d = d_base + w * 16 + (lane & 15);
  f32x4 acc[4] = {};
#pragma unroll
  for (int kk = 0; kk < 8; ++kk) {            // e-chunks of 32
    const int e0 = kk * 32 + (lane >> 4) * 8;
    float vb[8];
#pragma unroll
    for (int j = 0; j < 8; ++j) vb[j] = Wk[(size_t)(e0 + j) * 256 + d];
    bf16x8 b = pack8(vb);
#pragma unroll
    for (int m = 0; m < 4; ++m) {
      const int s = m * 16 + (lane & 15);
      float va[8];
#pragma unroll
      for (int j = 0; j < 8; ++j) va[j] = Pk[(size_t)(e0 + j) * 64 + s];
      bf16x8 a = pack8(va);
      acc[m] = __builtin_amdgcn_mfma_f32_16x16x32_bf16(a, b, acc[m], 0, 0, 0);
    }
  }
#pragma unroll
  for (int m = 0; m < 4; ++m)
#pragma unroll
    for (int j = 0; j < 4; ++j) {
      const int s = m * 16 + (lane >> 4) * 4 + j;
      Mk[(size_t)s * 256 + d] = f2bf1(acc[m][j]);
    }
}

// ---------- k_main: out[t][k][s] = inp_row . Mt[k][s][:] + b2[k][s] ----------
// grid (16,64); 4 waves; wave owns 64 tokens x 64 s; 4 blocks/CU resident.
// Mt_k (32KB) staged once via gload_lds (linear dest + inverse-swz source),
// swizzled ds_read.  A read global->reg, cvt_pk to bf16.
// MFMA operand order (Mt, tok): D row = s, col = token -> float4 stores.
__global__ __launch_bounds__(256, 4) void k_main(const float* __restrict__ inp,
                                                 const u16* __restrict__ Mt,
                                                 const float* __restrict__ b2,
                                                 float* __restrict__ out) {
  const int tb = blockIdx.x, k = blockIdx.y;
  const int tid = threadIdx.x, lane = tid & 63, w = tid >> 6;
  __shared__ __align__(16) u16 Bl[16384];     // [s=64][d=256] bf16, swizzled
  const u16* Mk = Mt + (size_t)k * 16384;
#pragma unroll
  for (int r = 0; r < 8; ++r) {               // 32 chunk-loads of 1KB/wave
    const int q = r * 256 + tid;              // 16B-chunk id, q in [0,2048)
    const int s = q >> 5, u = q & 31;         // 32 chunks per 512B row
    gload_lds16(Mk + (size_t)s * 256 + ((u ^ (s & 7)) * 8),
                (char*)Bl + r * 4096 + w * 1024);
  }
  const float* Ak = inp + ((size_t)k * 4096 + tb * 256 + w * 64) * 256;
  f32x4 acc[4][4] = {};                       // [m: tok-frag][n: s-frag]
  __syncthreads();                            // the only barrier

#pragma unroll
  for (int kk = 0; kk < 8; ++kk) {            // K-chunks of 32
    bf16x8 mt[4];
#pragma unroll
    for (int n = 0; n < 4; ++n) {             // s-rows
      const int s = n * 16 + (lane & 15);
      const int u = kk * 4 + (lane >> 4);
      mt[n] = *reinterpret_cast<const bf16x8*>(
          (const char*)Bl + s * 512 + ((u ^ (s & 7)) * 16));
    }
#pragma unroll
    for (int m = 0; m < 4; ++m) {             // token rows
      const float* ap = Ak + (size_t)(m * 16 + (lane & 15)) * 256 +
                        kk * 32 + (lane >> 4) * 8;
      float va[8];
      *reinterpret_cast<float4*>(&va[0]) = *reinterpret_cast<const float4*>(ap);
      *reinterpret_cast<float4*>(&va[4]) = *reinterpret_cast<const float4*>(ap + 4);
      bf16x8 a = pack8(va);
#pragma unroll
      for (int n = 0; n < 4; ++n)             // D[row=s, col=token]
        acc[m][n] = __builtin_amdgcn_mfma_f32_16x16x32_bf16(mt[n], a, acc[m][n], 0, 0, 0);
    }
  }

  const float* b2k = b2 + k * 64;
  const int T0 = tb * 256 + w * 64;
  float4 bv[4];
#pragma unroll
  for (int n = 0; n < 4; ++n)
    bv[n] = *reinterpret_cast<const float4*>(b2k + n * 16 + (lane >> 4) * 4);
#pragma unroll
  for (int m = 0; m < 4; ++m) {
    const int t = T0 + m * 16 + (lane & 15);
    float* op = out + (size_t)t * 4096 + k * 64;
#pragma unroll
    for (int n = 0; n < 4; ++n) {
      float4 r;
      r.x = acc[m][n][0] + bv[n].x;
      r.y = acc[m][n][1] + bv[n].y;
      r.z = acc[m][n][2] + bv[n].z;
      r.w = acc[m][n][3] + bv[n].w;
      *reinterpret_cast<float4*>(op + n * 16 + (lane >> 4) * 4) = r;
    }
  }
}

extern "C" void kernel_launch(void* const* d_in, const int* in_sizes, int n_in,
                              void* d_out, int out_size, void* d_ws, size_t ws_size,
                              hipStream_t stream) {
  const float* inp  = (const float*)d_in[0];
  // d_in[1] = fwd_expert_count (all 4096), d_in[5] = max_tokens: unused
  const float* W    = (const float*)d_in[2];
  const float* bias = (const float*)d_in[3];
  const float* P    = (const float*)d_in[4];   // [64,256,64]

  // ws: Mt bf16 [64][64][256] @0 (2 MB); b2 f32 [64][64] @2MB (16 KB)
  u16*   Mm = (u16*)d_ws;
  float* b2 = (float*)((char*)d_ws + 2097152);
  float* o  = (float*)d_out;

  k_b2  <<<dim3(64),     256, 0, stream>>>(bias, P, b2);
  k_m   <<<dim3(4, 64),  256, 0, stream>>>(P, W, Mm);
  k_main<<<dim3(16, 64), 256, 0, stream>>>(inp, Mm, b2, o);
}

// Round 4
// 89.955 us; speedup vs baseline: 1.0670x; 1.0584x over previous
//
#include <hip/hip_runtime.h>
#include <hip/hip_bf16.h>
#include <stdint.h>

// FMoELinearProj:
//   out[t,k,s] = sum_d inp[k*4096+t, d] * Mt[k,s,d] + b2[k,s]     (f32 out)
//   Mt[k,s,d]  = sum_e W[k,e,d] * P[k,e,s]      (bf16, precomputed in ws)
//   b2[k,s]    = sum_e bias[k,e] * P[k,e,s]     (f32, precomputed in ws)
// Shapes: inp [64*4096, 256] f32; W [64,256,256]; bias [64,256];
//         P [64,256,64]; out [4096,64,64] f32.  All experts full (4096 tok).

typedef unsigned int   u32;
typedef unsigned short u16;

typedef short bf16x8 __attribute__((ext_vector_type(8)));   // 8 bf16
typedef float f32x4  __attribute__((ext_vector_type(4)));

// Native casts -> compiler emits v_cvt_pk_bf16_f32 (RNE).
__device__ __forceinline__ bf16x8 pack8(const float* v) {
  union { __hip_bfloat16 h[8]; bf16x8 v8; } r;
#pragma unroll
  for (int j = 0; j < 8; ++j) r.h[j] = __float2bfloat16(v[j]);
  return r.v8;
}
__device__ __forceinline__ u16 f2bf1(float f) {
  union { __hip_bfloat16 h; u16 u; } r;
  r.h = __float2bfloat16(f);
  return r.u;
}
__device__ __forceinline__ u32 pk2(float a, float b) {     // lo=a, hi=b
  union { __hip_bfloat162 h; u32 u; } r;
  r.h.x = __float2bfloat16(a);
  r.h.y = __float2bfloat16(b);
  return r.u;
}
__device__ __forceinline__ void gload_lds16(const void* g, void* l) {
  __builtin_amdgcn_global_load_lds((__attribute__((address_space(1))) void*)g,
                                   (__attribute__((address_space(3))) void*)l,
                                   16, 0, 0);
}

// ---------- k_m (+fused b2): staged, coalesced, single-barrier ----------
// grid (5, 64): x<4 -> Mt d-tile of 64; x==4 -> b2 path.
// Mt path: stage WT[d][e] & PT[s][e] bf16 (32KB each) with c^(row&7) 16B-chunk
// swizzle; fully-coalesced float4 global reads; 1 barrier; 32 MFMA/wave.
__global__ __launch_bounds__(256, 2) void k_m(const float* __restrict__ P,
                                              const float* __restrict__ W,
                                              const float* __restrict__ bias,
                                              u16* __restrict__ Mt,
                                              float* __restrict__ b2) {
  const int k = blockIdx.y;
  const int tid = threadIdx.x;
  __shared__ __align__(16) unsigned char LDS[65536];
  const float* Pk = P + (size_t)k * 16384;                 // [e=256][s=64]

  if (blockIdx.x == 4) {                                   // ---- b2 path ----
    const int sq = tid & 15, ec = tid >> 4;                // s-quad, e-chunk
    const float* bk = bias + k * 256;
    f32x4 acc = {};
#pragma unroll
    for (int i = 0; i < 16; ++i) {
      const int e = ec * 16 + i;
      const float4 pv = *reinterpret_cast<const float4*>(Pk + (size_t)e * 64 + sq * 4);
      const float bv = bk[e];
      acc[0] = fmaf(bv, pv.x, acc[0]);
      acc[1] = fmaf(bv, pv.y, acc[1]);
      acc[2] = fmaf(bv, pv.z, acc[2]);
      acc[3] = fmaf(bv, pv.w, acc[3]);
    }
    float* red = reinterpret_cast<float*>(LDS);            // [16][64]
    *reinterpret_cast<f32x4*>(red + ec * 64 + sq * 4) = acc;
    __syncthreads();
    if (tid < 64) {
      float sum = 0.f;
#pragma unroll
      for (int c = 0; c < 16; ++c) sum += red[c * 64 + tid];
      b2[k * 64 + tid] = sum;
    }
    return;
  }

  // ---- Mt path ----
  const int d0 = blockIdx.x * 64;
  u32* WT = reinterpret_cast<u32*>(LDS);                   // [64][128 words]
  u32* PT = reinterpret_cast<u32*>(LDS + 32768);           // [64][128 words]
  const float* Wk = W + (size_t)k * 65536;                 // [e=256][d=256]
  const int lane = tid & 63, w = tid >> 6, q = lane & 15, g = lane >> 4;

#pragma unroll
  for (int r = 0; r < 8; ++r) {
    const int ep = r * 16 + w * 4 + g;                     // e-pair idx 0..127
    const float4 w0 = *reinterpret_cast<const float4*>(Wk + (size_t)(2 * ep) * 256 + d0 + 4 * q);
    const float4 w1 = *reinterpret_cast<const float4*>(Wk + (size_t)(2 * ep + 1) * 256 + d0 + 4 * q);
    const float4 p0 = *reinterpret_cast<const float4*>(Pk + (size_t)(2 * ep) * 64 + 4 * q);
    const float4 p1 = *reinterpret_cast<const float4*>(Pk + (size_t)(2 * ep + 1) * 64 + 4 * q);
    const int c = ep >> 2, cw = ep & 3;                    // 16B chunk, word-in-chunk
    const float wa[4] = {w0.x, w0.y, w0.z, w0.w};
    const float wb[4] = {w1.x, w1.y, w1.z, w1.w};
    const float pa[4] = {p0.x, p0.y, p0.z, p0.w};
    const float pb[4] = {p1.x, p1.y, p1.z, p1.w};
#pragma unroll
    for (int j = 0; j < 4; ++j) {
      const int rw = 4 * q + j;                            // LDS row
      const int sc = c ^ (rw & 7);                         // swizzled chunk
      WT[rw * 128 + sc * 4 + cw] = pk2(wa[j], wb[j]);
      PT[rw * 128 + sc * 4 + cw] = pk2(pa[j], pb[j]);
    }
  }
  __syncthreads();                                         // the only barrier

  f32x4 acc[4] = {};
  const int dl = w * 16 + q;                               // local d row
#pragma unroll
  for (int kk = 0; kk < 8; ++kk) {
    const bf16x8 bfr = *reinterpret_cast<const bf16x8*>(
        reinterpret_cast<const char*>(WT) + dl * 512 + (((kk * 4 + g) ^ (dl & 7)) * 16));
#pragma unroll
    for (int m = 0; m < 4; ++m) {
      const int s = m * 16 + q;
      const bf16x8 afr = *reinterpret_cast<const bf16x8*>(
          reinterpret_cast<const char*>(PT) + s * 512 + (((kk * 4 + g) ^ (s & 7)) * 16));
      acc[m] = __builtin_amdgcn_mfma_f32_16x16x32_bf16(afr, bfr, acc[m], 0, 0, 0);
    }
  }
  u16* Mk = Mt + (size_t)k * 16384;                        // [s=64][d=256]
#pragma unroll
  for (int m = 0; m < 4; ++m)
#pragma unroll
    for (int j = 0; j < 4; ++j) {
      const int s = m * 16 + g * 4 + j;
      Mk[(size_t)s * 256 + d0 + w * 16 + q] = f2bf1(acc[m][j]);
    }
}

// ---------- k_main: out[t][k][s] = inp_row . Mt[k][s][:] + b2[k][s] ----------
// grid (16,64); 4 waves; wave owns 64 tokens x 64 s; 4 blocks/CU resident.
// Mt_k (32KB) staged once via gload_lds (linear dest + inverse-swz source),
// swizzled ds_read.  A read global->reg, cvt_pk to bf16.
// MFMA operand order (Mt, tok): D row = s, col = token -> float4 stores.
__global__ __launch_bounds__(256, 4) void k_main(const float* __restrict__ inp,
                                                 const u16* __restrict__ Mt,
                                                 const float* __restrict__ b2,
                                                 float* __restrict__ out) {
  const int tb = blockIdx.x, k = blockIdx.y;
  const int tid = threadIdx.x, lane = tid & 63, w = tid >> 6;
  __shared__ __align__(16) u16 Bl[16384];     // [s=64][d=256] bf16, swizzled
  const u16* Mk = Mt + (size_t)k * 16384;
#pragma unroll
  for (int r = 0; r < 8; ++r) {               // 32 chunk-loads of 1KB/wave
    const int q = r * 256 + tid;              // 16B-chunk id, q in [0,2048)
    const int s = q >> 5, u = q & 31;         // 32 chunks per 512B row
    gload_lds16(Mk + (size_t)s * 256 + ((u ^ (s & 7)) * 8),
                (char*)Bl + r * 4096 + w * 1024);
  }
  const float* Ak = inp + ((size_t)k * 4096 + tb * 256 + w * 64) * 256;
  f32x4 acc[4][4] = {};                       // [m: tok-frag][n: s-frag]
  __syncthreads();                            // the only barrier

#pragma unroll
  for (int kk = 0; kk < 8; ++kk) {            // K-chunks of 32
    bf16x8 mt[4];
#pragma unroll
    for (int n = 0; n < 4; ++n) {             // s-rows
      const int s = n * 16 + (lane & 15);
      const int u = kk * 4 + (lane >> 4);
      mt[n] = *reinterpret_cast<const bf16x8*>(
          (const char*)Bl + s * 512 + ((u ^ (s & 7)) * 16));
    }
#pragma unroll
    for (int m = 0; m < 4; ++m) {             // token rows
      const float* ap = Ak + (size_t)(m * 16 + (lane & 15)) * 256 +
                        kk * 32 + (lane >> 4) * 8;
      float va[8];
      *reinterpret_cast<float4*>(&va[0]) = *reinterpret_cast<const float4*>(ap);
      *reinterpret_cast<float4*>(&va[4]) = *reinterpret_cast<const float4*>(ap + 4);
      bf16x8 a = pack8(va);
#pragma unroll
      for (int n = 0; n < 4; ++n)             // D[row=s, col=token]
        acc[m][n] = __builtin_amdgcn_mfma_f32_16x16x32_bf16(mt[n], a, acc[m][n], 0, 0, 0);
    }
  }

  const float* b2k = b2 + k * 64;
  const int T0 = tb * 256 + w * 64;
  float4 bv[4];
#pragma unroll
  for (int n = 0; n < 4; ++n)
    bv[n] = *reinterpret_cast<const float4*>(b2k + n * 16 + (lane >> 4) * 4);
#pragma unroll
  for (int m = 0; m < 4; ++m) {
    const int t = T0 + m * 16 + (lane & 15);
    float* op = out + (size_t)t * 4096 + k * 64;
#pragma unroll
    for (int n = 0; n < 4; ++n) {
      float4 r;
      r.x = acc[m][n][0] + bv[n].x;
      r.y = acc[m][n][1] + bv[n].y;
      r.z = acc[m][n][2] + bv[n].z;
      r.w = acc[m][n][3] + bv[n].w;
      *reinterpret_cast<float4*>(op + n * 16 + (lane >> 4) * 4) = r;
    }
  }
}

extern "C" void kernel_launch(void* const* d_in, const int* in_sizes, int n_in,
                              void* d_out, int out_size, void* d_ws, size_t ws_size,
                              hipStream_t stream) {
  const float* inp  = (const float*)d_in[0];
  // d_in[1] = fwd_expert_count (all 4096), d_in[5] = max_tokens: unused
  const float* W    = (const float*)d_in[2];
  const float* bias = (const float*)d_in[3];
  const float* P    = (const float*)d_in[4];   // [64,256,64]

  // ws: Mt bf16 [64][64][256] @0 (2 MB); b2 f32 [64][64] @2MB (16 KB)
  u16*   Mm = (u16*)d_ws;
  float* b2 = (float*)((char*)d_ws + 2097152);
  float* o  = (float*)d_out;

  k_m   <<<dim3(5, 64),  256, 0, stream>>>(P, W, bias, Mm, b2);
  k_main<<<dim3(16, 64), 256, 0, stream>>>(inp, Mm, b2, o);
}

// Round 5
// 89.903 us; speedup vs baseline: 1.0676x; 1.0006x over previous
//
#include <hip/hip_runtime.h>
#include <hip/hip_bf16.h>
#include <stdint.h>

// FMoELinearProj:
//   out[t,k,s] = sum_d inp[k*4096+t, d] * Mt[k,s,d] + b2[k,s]     (f32 out)
//   Mt[k,s,d]  = sum_e W[k,e,d] * P[k,e,s]      (bf16, precomputed in ws)
//   b2[k,s]    = sum_e bias[k,e] * P[k,e,s]     (f32, precomputed in ws)
// Shapes: inp [64*4096, 256] f32; W [64,256,256]; bias [64,256];
//         P [64,256,64]; out [4096,64,64] f32.  All experts full (4096 tok).

typedef unsigned int   u32;
typedef unsigned short u16;

typedef short bf16x8 __attribute__((ext_vector_type(8)));   // 8 bf16
typedef float f32x4  __attribute__((ext_vector_type(4)));

// Native casts -> compiler emits v_cvt_pk_bf16_f32 (RNE).
__device__ __forceinline__ bf16x8 pack8(const float* v) {
  union { __hip_bfloat16 h[8]; bf16x8 v8; } r;
#pragma unroll
  for (int j = 0; j < 8; ++j) r.h[j] = __float2bfloat16(v[j]);
  return r.v8;
}
__device__ __forceinline__ u16 f2bf1(float f) {
  union { __hip_bfloat16 h; u16 u; } r;
  r.h = __float2bfloat16(f);
  return r.u;
}
__device__ __forceinline__ u32 pk2(float a, float b) {     // lo=a, hi=b
  union { __hip_bfloat162 h; u32 u; } r;
  r.h.x = __float2bfloat16(a);
  r.h.y = __float2bfloat16(b);
  return r.u;
}
__device__ __forceinline__ void gload_lds16(const void* g, void* l) {
  __builtin_amdgcn_global_load_lds((__attribute__((address_space(1))) void*)g,
                                   (__attribute__((address_space(3))) void*)l,
                                   16, 0, 0);
}

// ---------- k_m (+fused b2): staged, coalesced, single-barrier ----------
// grid (5, 64): x<4 -> Mt d-tile of 64; x==4 -> b2 path.  (verified r4)
__global__ __launch_bounds__(256, 2) void k_m(const float* __restrict__ P,
                                              const float* __restrict__ W,
                                              const float* __restrict__ bias,
                                              u16* __restrict__ Mt,
                                              float* __restrict__ b2) {
  const int k = blockIdx.y;
  const int tid = threadIdx.x;
  __shared__ __align__(16) unsigned char LDS[65536];
  const float* Pk = P + (size_t)k * 16384;                 // [e=256][s=64]

  if (blockIdx.x == 4) {                                   // ---- b2 path ----
    const int sq = tid & 15, ec = tid >> 4;
    const float* bk = bias + k * 256;
    f32x4 acc = {};
#pragma unroll
    for (int i = 0; i < 16; ++i) {
      const int e = ec * 16 + i;
      const float4 pv = *reinterpret_cast<const float4*>(Pk + (size_t)e * 64 + sq * 4);
      const float bv = bk[e];
      acc[0] = fmaf(bv, pv.x, acc[0]);
      acc[1] = fmaf(bv, pv.y, acc[1]);
      acc[2] = fmaf(bv, pv.z, acc[2]);
      acc[3] = fmaf(bv, pv.w, acc[3]);
    }
    float* red = reinterpret_cast<float*>(LDS);            // [16][64]
    *reinterpret_cast<f32x4*>(red + ec * 64 + sq * 4) = acc;
    __syncthreads();
    if (tid < 64) {
      float sum = 0.f;
#pragma unroll
      for (int c = 0; c < 16; ++c) sum += red[c * 64 + tid];
      b2[k * 64 + tid] = sum;
    }
    return;
  }

  // ---- Mt path ----
  const int d0 = blockIdx.x * 64;
  u32* WT = reinterpret_cast<u32*>(LDS);                   // [64][128 words]
  u32* PT = reinterpret_cast<u32*>(LDS + 32768);           // [64][128 words]
  const float* Wk = W + (size_t)k * 65536;                 // [e=256][d=256]
  const int lane = tid & 63, w = tid >> 6, q = lane & 15, g = lane >> 4;

#pragma unroll
  for (int r = 0; r < 8; ++r) {
    const int ep = r * 16 + w * 4 + g;                     // e-pair idx 0..127
    const float4 w0 = *reinterpret_cast<const float4*>(Wk + (size_t)(2 * ep) * 256 + d0 + 4 * q);
    const float4 w1 = *reinterpret_cast<const float4*>(Wk + (size_t)(2 * ep + 1) * 256 + d0 + 4 * q);
    const float4 p0 = *reinterpret_cast<const float4*>(Pk + (size_t)(2 * ep) * 64 + 4 * q);
    const float4 p1 = *reinterpret_cast<const float4*>(Pk + (size_t)(2 * ep + 1) * 64 + 4 * q);
    const int c = ep >> 2, cw = ep & 3;
    const float wa[4] = {w0.x, w0.y, w0.z, w0.w};
    const float wb[4] = {w1.x, w1.y, w1.z, w1.w};
    const float pa[4] = {p0.x, p0.y, p0.z, p0.w};
    const float pb[4] = {p1.x, p1.y, p1.z, p1.w};
#pragma unroll
    for (int j = 0; j < 4; ++j) {
      const int rw = 4 * q + j;
      const int sc = c ^ (rw & 7);
      WT[rw * 128 + sc * 4 + cw] = pk2(wa[j], wb[j]);
      PT[rw * 128 + sc * 4 + cw] = pk2(pa[j], pb[j]);
    }
  }
  __syncthreads();

  f32x4 acc[4] = {};
  const int dl = w * 16 + q;
#pragma unroll
  for (int kk = 0; kk < 8; ++kk) {
    const bf16x8 bfr = *reinterpret_cast<const bf16x8*>(
        reinterpret_cast<const char*>(WT) + dl * 512 + (((kk * 4 + g) ^ (dl & 7)) * 16));
#pragma unroll
    for (int m = 0; m < 4; ++m) {
      const int s = m * 16 + q;
      const bf16x8 afr = *reinterpret_cast<const bf16x8*>(
          reinterpret_cast<const char*>(PT) + s * 512 + (((kk * 4 + g) ^ (s & 7)) * 16));
      acc[m] = __builtin_amdgcn_mfma_f32_16x16x32_bf16(afr, bfr, acc[m], 0, 0, 0);
    }
  }
  u16* Mk = Mt + (size_t)k * 16384;                        // [s=64][d=256]
#pragma unroll
  for (int m = 0; m < 4; ++m)
#pragma unroll
    for (int j = 0; j < 4; ++j) {
      const int s = m * 16 + g * 4 + j;
      Mk[(size_t)s * 256 + d0 + w * 16 + q] = f2bf1(acc[m][j]);
    }
}

// ---------- k_main: out[t][k][s] = inp_row . Mt[k][s][:] + b2[k][s] ----------
// grid (64, 64); 4 waves; block = 64 tok x 64 s; wave = 16 tok x 64 s.
// A (f32) staged via gload_lds in 64-d chunks (16KB, double-buffered):
// VGPR-free deep load queue -> ~32KB/CU in flight (2 blocks/CU alternate).
// 16B-chunk XOR swizzle via inverse-permuted global source (rule #21).
// Mt (32KB bf16) staged once as before.  LDS 64KB -> 2 blocks/CU.
__global__ __launch_bounds__(256, 2) void k_main(const float* __restrict__ inp,
                                                 const u16* __restrict__ Mt,
                                                 const float* __restrict__ b2,
                                                 float* __restrict__ out) {
  const int tb = blockIdx.x, k = blockIdx.y;
  const int tid = threadIdx.x, lane = tid & 63, w = tid >> 6;
  const int q = lane & 15, g = lane >> 4;
  __shared__ __align__(16) unsigned char LDS[65536];
  u16* Bl = reinterpret_cast<u16*>(LDS);       // Mt [s=64][d=256] bf16, swz
  unsigned char* const Ab[2] = {LDS + 32768, LDS + 49152};  // f32 [64tok][64d]

  const u16* Mk = Mt + (size_t)k * 16384;
#pragma unroll
  for (int r = 0; r < 8; ++r) {                // Mt: 32 x 1KB chunk-loads
    const int qq = r * 256 + tid;
    const int s = qq >> 5, u = qq & 31;
    gload_lds16(Mk + (size_t)s * 256 + ((u ^ (s & 7)) * 8),
                (char*)Bl + r * 4096 + w * 1024);
  }

  const float* Ak = inp + ((size_t)k * 4096 + (size_t)tb * 64) * 256;
  // stage A chunk c (d in [c*64, c*64+64)) for this wave's 16 tokens.
  // instr r covers tokens w*16+r*4 .. +4; lane: tok += g, 16B chunk q.
  // source chunk = q ^ (tok_local & 15) so LDS pos q holds that chunk.
  auto stageA = [&](int c, unsigned char* A) {
#pragma unroll
    for (int r = 0; r < 4; ++r) {
      const int tl = w * 16 + r * 4 + g;       // local token
      gload_lds16(Ak + (size_t)tl * 256 + c * 64 + ((q ^ ((r * 4 + g) & 15)) * 4),
                  A + (w * 16 + r * 4) * 256);
    }
  };

  stageA(0, Ab[0]);
  f32x4 acc[4] = {};                           // wave: tok=lane&15, s: 4 frags
  const int tl = w * 16 + q;                   // this lane's token row in LDS
  __syncthreads();                             // Mt + chunk0 ready

#pragma unroll
  for (int c = 0; c < 4; ++c) {
    if (c < 3) stageA(c + 1, Ab[(c + 1) & 1]);
    const unsigned char* A = Ab[c & 1];
#pragma unroll
    for (int ks = 0; ks < 2; ++ks) {           // K-sub of 32 d
      const int kkg = c * 2 + ks;              // global K-chunk 0..7
      bf16x8 mt[4];
#pragma unroll
      for (int n = 0; n < 4; ++n) {
        const int s = n * 16 + q;
        mt[n] = *reinterpret_cast<const bf16x8*>(
            (const char*)Bl + s * 512 + (((kkg * 4 + g) ^ (s & 7)) * 16));
      }
      const int cg = ks * 8 + g * 2;           // global 16B-chunk in row
      f32x4 v0 = *reinterpret_cast<const f32x4*>(A + tl * 256 + (((cg + 0) ^ q) * 16));
      f32x4 v1 = *reinterpret_cast<const f32x4*>(A + tl * 256 + (((cg + 1) ^ q) * 16));
      float va[8] = {v0[0], v0[1], v0[2], v0[3], v1[0], v1[1], v1[2], v1[3]};
      const bf16x8 a = pack8(va);
#pragma unroll
      for (int n = 0; n < 4; ++n)              // D: row=s, col=token
        acc[n] = __builtin_amdgcn_mfma_f32_16x16x32_bf16(mt[n], a, acc[n], 0, 0, 0);
    }
    __syncthreads();                           // chunk c+1 ready, buf reusable
  }

  const float* b2k = b2 + k * 64;
  const int t = tb * 64 + w * 16 + q;
  float* op = out + (size_t)t * 4096 + k * 64;
#pragma unroll
  for (int n = 0; n < 4; ++n) {
    const float4 bv = *reinterpret_cast<const float4*>(b2k + n * 16 + g * 4);
    float4 r;
    r.x = acc[n][0] + bv.x;
    r.y = acc[n][1] + bv.y;
    r.z = acc[n][2] + bv.z;
    r.w = acc[n][3] + bv.w;
    *reinterpret_cast<float4*>(op + n * 16 + g * 4) = r;
  }
}

extern "C" void kernel_launch(void* const* d_in, const int* in_sizes, int n_in,
                              void* d_out, int out_size, void* d_ws, size_t ws_size,
                              hipStream_t stream) {
  const float* inp  = (const float*)d_in[0];
  // d_in[1] = fwd_expert_count (all 4096), d_in[5] = max_tokens: unused
  const float* W    = (const float*)d_in[2];
  const float* bias = (const float*)d_in[3];
  const float* P    = (const float*)d_in[4];   // [64,256,64]

  // ws: Mt bf16 [64][64][256] @0 (2 MB); b2 f32 [64][64] @2MB (16 KB)
  u16*   Mm = (u16*)d_ws;
  float* b2 = (float*)((char*)d_ws + 2097152);
  float* o  = (float*)d_out;

  k_m   <<<dim3(5, 64),  256, 0, stream>>>(P, W, bias, Mm, b2);
  k_main<<<dim3(64, 64), 256, 0, stream>>>(inp, Mm, b2, o);
}

// Round 6
// 83.494 us; speedup vs baseline: 1.1496x; 1.0768x over previous
//
#include <hip/hip_runtime.h>
#include <hip/hip_bf16.h>
#include <stdint.h>

// FMoELinearProj:
//   out[t,k,s] = sum_d inp[k*4096+t, d] * Mt[k,s,d] + b2[k,s]     (f32 out)
//   Mt[k,s,d]  = sum_e W[k,e,d] * P[k,e,s]      (bf16, precomputed in ws)
//   b2[k,s]    = sum_e bias[k,e] * P[k,e,s]     (f32, precomputed in ws)
// Shapes: inp [64*4096, 256] f32; W [64,256,256]; bias [64,256];
//         P [64,256,64]; out [4096,64,64] f32.  All experts full (4096 tok).

typedef unsigned int   u32;
typedef unsigned short u16;

typedef short bf16x8 __attribute__((ext_vector_type(8)));   // 8 bf16
typedef float f32x4  __attribute__((ext_vector_type(4)));

// Native casts -> compiler emits v_cvt_pk_bf16_f32 (RNE).
__device__ __forceinline__ bf16x8 pack8(const float* v) {
  union { __hip_bfloat16 h[8]; bf16x8 v8; } r;
#pragma unroll
  for (int j = 0; j < 8; ++j) r.h[j] = __float2bfloat16(v[j]);
  return r.v8;
}
__device__ __forceinline__ u16 f2bf1(float f) {
  union { __hip_bfloat16 h; u16 u; } r;
  r.h = __float2bfloat16(f);
  return r.u;
}
__device__ __forceinline__ u32 pk2(float a, float b) {     // lo=a, hi=b
  union { __hip_bfloat162 h; u32 u; } r;
  r.h.x = __float2bfloat16(a);
  r.h.y = __float2bfloat16(b);
  return r.u;
}
__device__ __forceinline__ void gload_lds16(const void* g, void* l) {
  __builtin_amdgcn_global_load_lds((__attribute__((address_space(1))) void*)g,
                                   (__attribute__((address_space(3))) void*)l,
                                   16, 0, 0);
}

// ---------- k_m (+fused b2): staged, coalesced, single-barrier ----------
// grid (5, 64): x<4 -> Mt d-tile of 64; x==4 -> b2 path.  (verified r4)
__global__ __launch_bounds__(256, 2) void k_m(const float* __restrict__ P,
                                              const float* __restrict__ W,
                                              const float* __restrict__ bias,
                                              u16* __restrict__ Mt,
                                              float* __restrict__ b2) {
  const int k = blockIdx.y;
  const int tid = threadIdx.x;
  __shared__ __align__(16) unsigned char LDS[65536];
  const float* Pk = P + (size_t)k * 16384;                 // [e=256][s=64]

  if (blockIdx.x == 4) {                                   // ---- b2 path ----
    const int sq = tid & 15, ec = tid >> 4;
    const float* bk = bias + k * 256;
    f32x4 acc = {};
#pragma unroll
    for (int i = 0; i < 16; ++i) {
      const int e = ec * 16 + i;
      const float4 pv = *reinterpret_cast<const float4*>(Pk + (size_t)e * 64 + sq * 4);
      const float bv = bk[e];
      acc[0] = fmaf(bv, pv.x, acc[0]);
      acc[1] = fmaf(bv, pv.y, acc[1]);
      acc[2] = fmaf(bv, pv.z, acc[2]);
      acc[3] = fmaf(bv, pv.w, acc[3]);
    }
    float* red = reinterpret_cast<float*>(LDS);            // [16][64]
    *reinterpret_cast<f32x4*>(red + ec * 64 + sq * 4) = acc;
    __syncthreads();
    if (tid < 64) {
      float sum = 0.f;
#pragma unroll
      for (int c = 0; c < 16; ++c) sum += red[c * 64 + tid];
      b2[k * 64 + tid] = sum;
    }
    return;
  }

  // ---- Mt path ----
  const int d0 = blockIdx.x * 64;
  u32* WT = reinterpret_cast<u32*>(LDS);                   // [64][128 words]
  u32* PT = reinterpret_cast<u32*>(LDS + 32768);           // [64][128 words]
  const float* Wk = W + (size_t)k * 65536;                 // [e=256][d=256]
  const int lane = tid & 63, w = tid >> 6, q = lane & 15, g = lane >> 4;

#pragma unroll
  for (int r = 0; r < 8; ++r) {
    const int ep = r * 16 + w * 4 + g;                     // e-pair idx 0..127
    const float4 w0 = *reinterpret_cast<const float4*>(Wk + (size_t)(2 * ep) * 256 + d0 + 4 * q);
    const float4 w1 = *reinterpret_cast<const float4*>(Wk + (size_t)(2 * ep + 1) * 256 + d0 + 4 * q);
    const float4 p0 = *reinterpret_cast<const float4*>(Pk + (size_t)(2 * ep) * 64 + 4 * q);
    const float4 p1 = *reinterpret_cast<const float4*>(Pk + (size_t)(2 * ep + 1) * 64 + 4 * q);
    const int c = ep >> 2, cw = ep & 3;
    const float wa[4] = {w0.x, w0.y, w0.z, w0.w};
    const float wb[4] = {w1.x, w1.y, w1.z, w1.w};
    const float pa[4] = {p0.x, p0.y, p0.z, p0.w};
    const float pb[4] = {p1.x, p1.y, p1.z, p1.w};
#pragma unroll
    for (int j = 0; j < 4; ++j) {
      const int rw = 4 * q + j;
      const int sc = c ^ (rw & 7);
      WT[rw * 128 + sc * 4 + cw] = pk2(wa[j], wb[j]);
      PT[rw * 128 + sc * 4 + cw] = pk2(pa[j], pb[j]);
    }
  }
  __syncthreads();

  f32x4 acc[4] = {};
  const int dl = w * 16 + q;
#pragma unroll
  for (int kk = 0; kk < 8; ++kk) {
    const bf16x8 bfr = *reinterpret_cast<const bf16x8*>(
        reinterpret_cast<const char*>(WT) + dl * 512 + (((kk * 4 + g) ^ (dl & 7)) * 16));
#pragma unroll
    for (int m = 0; m < 4; ++m) {
      const int s = m * 16 + q;
      const bf16x8 afr = *reinterpret_cast<const bf16x8*>(
          reinterpret_cast<const char*>(PT) + s * 512 + (((kk * 4 + g) ^ (s & 7)) * 16));
      acc[m] = __builtin_amdgcn_mfma_f32_16x16x32_bf16(afr, bfr, acc[m], 0, 0, 0);
    }
  }
  u16* Mk = Mt + (size_t)k * 16384;                        // [s=64][d=256]
#pragma unroll
  for (int m = 0; m < 4; ++m)
#pragma unroll
    for (int j = 0; j < 4; ++j) {
      const int s = m * 16 + g * 4 + j;
      Mk[(size_t)s * 256 + d0 + w * 16 + q] = f2bf1(acc[m][j]);
    }
}

// ---------- k_main: out[t][k][s] = inp_row . Mt[k][s][:] + b2[k][s] ----------
// grid (64, 64); 4 waves; wave = 16 tokens x 64 s.
// All 16 A float4 loads per lane issued UP-FRONT into VGPRs (16KB/wave in
// flight, zero K-loop barriers).  Mt_k (32KB) staged once via gload_lds with
// the verified swizzle; one barrier total.  Epilogue bounces acc through a
// per-wave 4KB LDS region (XOR chunk swizzle) so each global store instr
// writes 4 x 256B contiguous segments (was 16 x 64B scattered).
// LDS 48KB -> 3 blocks/CU.
__global__ __launch_bounds__(256, 2) void k_main(const float* __restrict__ inp,
                                                 const u16* __restrict__ Mt,
                                                 const float* __restrict__ b2,
                                                 float* __restrict__ out) {
  const int tb = blockIdx.x, k = blockIdx.y;
  const int tid = threadIdx.x, lane = tid & 63, w = tid >> 6;
  const int q = lane & 15, g = lane >> 4;
  __shared__ __align__(16) unsigned char LDS[49152];
  u16* Bl = reinterpret_cast<u16*>(LDS);                   // Mt 32KB, swizzled
  float* Wb = reinterpret_cast<float*>(LDS + 32768 + w * 4096); // wave bounce

  // 1) issue ALL A loads for this lane's token (tb*64 + w*16 + q)
  const float* Ak = inp + ((size_t)k * 4096 + (size_t)tb * 64 + w * 16 + q) * 256;
  float4 apre[16];
#pragma unroll
  for (int kk = 0; kk < 8; ++kk) {
    apre[2 * kk]     = *reinterpret_cast<const float4*>(Ak + kk * 32 + g * 8);
    apre[2 * kk + 1] = *reinterpret_cast<const float4*>(Ak + kk * 32 + g * 8 + 4);
  }

  // 2) stage Mt_k (32KB): gload_lds linear dest + inverse-swizzled source
  const u16* Mk = Mt + (size_t)k * 16384;
#pragma unroll
  for (int r = 0; r < 8; ++r) {
    const int qq = r * 256 + tid;
    const int s = qq >> 5, u = qq & 31;
    gload_lds16(Mk + (size_t)s * 256 + ((u ^ (s & 7)) * 8),
                (char*)Bl + r * 4096 + w * 1024);
  }
  f32x4 acc[4] = {};
  __syncthreads();                                         // the only barrier

  // 3) K loop: register A, swizzled LDS Mt frags, no barriers
#pragma unroll
  for (int kk = 0; kk < 8; ++kk) {
    bf16x8 mt[4];
#pragma unroll
    for (int n = 0; n < 4; ++n) {
      const int s = n * 16 + q;
      mt[n] = *reinterpret_cast<const bf16x8*>(
          (const char*)Bl + s * 512 + (((kk * 4 + g) ^ (s & 7)) * 16));
    }
    const float va[8] = {apre[2 * kk][0],     apre[2 * kk][1],
                         apre[2 * kk][2],     apre[2 * kk][3],
                         apre[2 * kk + 1][0], apre[2 * kk + 1][1],
                         apre[2 * kk + 1][2], apre[2 * kk + 1][3]};
    const bf16x8 a = pack8(va);
#pragma unroll
    for (int n = 0; n < 4; ++n)              // D: row=s, col=token
      acc[n] = __builtin_amdgcn_mfma_f32_16x16x32_bf16(mt[n], a, acc[n], 0, 0, 0);
  }

  // 4) epilogue: +b2, swizzled LDS bounce, 256B-contiguous stores
  const float* b2k = b2 + k * 64;
#pragma unroll
  for (int n = 0; n < 4; ++n) {
    const float4 bv = *reinterpret_cast<const float4*>(b2k + n * 16 + g * 4);
    f32x4 r;
    r[0] = acc[n][0] + bv.x;
    r[1] = acc[n][1] + bv.y;
    r[2] = acc[n][2] + bv.z;
    r[3] = acc[n][3] + bv.w;
    const int ch = n * 4 + g;                // 16B s-chunk within token row
    *reinterpret_cast<f32x4*>(Wb + q * 64 + ((ch ^ q) * 4)) = r;
  }
#pragma unroll
  for (int j = 0; j < 4; ++j) {
    const int tq = j * 4 + g;                // local token
    const f32x4 v = *reinterpret_cast<const f32x4*>(Wb + tq * 64 + ((q ^ tq) * 4));
    const int t = tb * 64 + w * 16 + tq;
    *reinterpret_cast<f32x4*>(out + (size_t)t * 4096 + k * 64 + q * 4) = v;
  }
}

extern "C" void kernel_launch(void* const* d_in, const int* in_sizes, int n_in,
                              void* d_out, int out_size, void* d_ws, size_t ws_size,
                              hipStream_t stream) {
  const float* inp  = (const float*)d_in[0];
  // d_in[1] = fwd_expert_count (all 4096), d_in[5] = max_tokens: unused
  const float* W    = (const float*)d_in[2];
  const float* bias = (const float*)d_in[3];
  const float* P    = (const float*)d_in[4];   // [64,256,64]

  // ws: Mt bf16 [64][64][256] @0 (2 MB); b2 f32 [64][64] @2MB (16 KB)
  u16*   Mm = (u16*)d_ws;
  float* b2 = (float*)((char*)d_ws + 2097152);
  float* o  = (float*)d_out;

  k_m   <<<dim3(5, 64),  256, 0, stream>>>(P, W, bias, Mm, b2);
  k_main<<<dim3(64, 64), 256, 0, stream>>>(inp, Mm, b2, o);
}

// Round 7
// 78.612 us; speedup vs baseline: 1.2210x; 1.0621x over previous
//
#include <hip/hip_runtime.h>
#include <hip/hip_bf16.h>
#include <stdint.h>

// FMoELinearProj:
//   out[t,k,s] = sum_d inp[k*4096+t, d] * Mt[k,s,d] + b2[k,s]     (f32 out)
//   Mt[k,s,d]  = sum_e W[k,e,d] * P[k,e,s]      (bf16, precomputed in ws)
//   b2[k,s]    = sum_e bias[k,e] * P[k,e,s]     (f32, precomputed in ws)
// Shapes: inp [64*4096, 256] f32; W [64,256,256]; bias [64,256];
//         P [64,256,64]; out [4096,64,64] f32.  All experts full (4096 tok).

typedef unsigned int   u32;
typedef unsigned short u16;

typedef short bf16x8 __attribute__((ext_vector_type(8)));   // 8 bf16
typedef float f32x4  __attribute__((ext_vector_type(4)));

// Native casts -> compiler emits v_cvt_pk_bf16_f32 (RNE).
__device__ __forceinline__ bf16x8 pack8(const float* v) {
  union { __hip_bfloat16 h[8]; bf16x8 v8; } r;
#pragma unroll
  for (int j = 0; j < 8; ++j) r.h[j] = __float2bfloat16(v[j]);
  return r.v8;
}
__device__ __forceinline__ u16 f2bf1(float f) {
  union { __hip_bfloat16 h; u16 u; } r;
  r.h = __float2bfloat16(f);
  return r.u;
}
__device__ __forceinline__ u32 pk2(float a, float b) {     // lo=a, hi=b
  union { __hip_bfloat162 h; u32 u; } r;
  r.h.x = __float2bfloat16(a);
  r.h.y = __float2bfloat16(b);
  return r.u;
}
__device__ __forceinline__ void gload_lds16(const void* g, void* l) {
  __builtin_amdgcn_global_load_lds((__attribute__((address_space(1))) void*)g,
                                   (__attribute__((address_space(3))) void*)l,
                                   16, 0, 0);
}

// ---------- k_m (+fused b2): staged, coalesced, single-barrier ----------
// grid (5, 64): x<4 -> Mt d-tile of 64; x==4 -> b2 path.  (verified r4)
__global__ __launch_bounds__(256, 2) void k_m(const float* __restrict__ P,
                                              const float* __restrict__ W,
                                              const float* __restrict__ bias,
                                              u16* __restrict__ Mt,
                                              float* __restrict__ b2) {
  const int k = blockIdx.y;
  const int tid = threadIdx.x;
  __shared__ __align__(16) unsigned char LDS[65536];
  const float* Pk = P + (size_t)k * 16384;                 // [e=256][s=64]

  if (blockIdx.x == 4) {                                   // ---- b2 path ----
    const int sq = tid & 15, ec = tid >> 4;
    const float* bk = bias + k * 256;
    f32x4 acc = {};
#pragma unroll
    for (int i = 0; i < 16; ++i) {
      const int e = ec * 16 + i;
      const float4 pv = *reinterpret_cast<const float4*>(Pk + (size_t)e * 64 + sq * 4);
      const float bv = bk[e];
      acc[0] = fmaf(bv, pv.x, acc[0]);
      acc[1] = fmaf(bv, pv.y, acc[1]);
      acc[2] = fmaf(bv, pv.z, acc[2]);
      acc[3] = fmaf(bv, pv.w, acc[3]);
    }
    float* red = reinterpret_cast<float*>(LDS);            // [16][64]
    *reinterpret_cast<f32x4*>(red + ec * 64 + sq * 4) = acc;
    __syncthreads();
    if (tid < 64) {
      float sum = 0.f;
#pragma unroll
      for (int c = 0; c < 16; ++c) sum += red[c * 64 + tid];
      b2[k * 64 + tid] = sum;
    }
    return;
  }

  // ---- Mt path ----
  const int d0 = blockIdx.x * 64;
  u32* WT = reinterpret_cast<u32*>(LDS);                   // [64][128 words]
  u32* PT = reinterpret_cast<u32*>(LDS + 32768);           // [64][128 words]
  const float* Wk = W + (size_t)k * 65536;                 // [e=256][d=256]
  const int lane = tid & 63, w = tid >> 6, q = lane & 15, g = lane >> 4;

#pragma unroll
  for (int r = 0; r < 8; ++r) {
    const int ep = r * 16 + w * 4 + g;                     // e-pair idx 0..127
    const float4 w0 = *reinterpret_cast<const float4*>(Wk + (size_t)(2 * ep) * 256 + d0 + 4 * q);
    const float4 w1 = *reinterpret_cast<const float4*>(Wk + (size_t)(2 * ep + 1) * 256 + d0 + 4 * q);
    const float4 p0 = *reinterpret_cast<const float4*>(Pk + (size_t)(2 * ep) * 64 + 4 * q);
    const float4 p1 = *reinterpret_cast<const float4*>(Pk + (size_t)(2 * ep + 1) * 64 + 4 * q);
    const int c = ep >> 2, cw = ep & 3;
    const float wa[4] = {w0.x, w0.y, w0.z, w0.w};
    const float wb[4] = {w1.x, w1.y, w1.z, w1.w};
    const float pa[4] = {p0.x, p0.y, p0.z, p0.w};
    const float pb[4] = {p1.x, p1.y, p1.z, p1.w};
#pragma unroll
    for (int j = 0; j < 4; ++j) {
      const int rw = 4 * q + j;
      const int sc = c ^ (rw & 7);
      WT[rw * 128 + sc * 4 + cw] = pk2(wa[j], wb[j]);
      PT[rw * 128 + sc * 4 + cw] = pk2(pa[j], pb[j]);
    }
  }
  __syncthreads();

  f32x4 acc[4] = {};
  const int dl = w * 16 + q;
#pragma unroll
  for (int kk = 0; kk < 8; ++kk) {
    const bf16x8 bfr = *reinterpret_cast<const bf16x8*>(
        reinterpret_cast<const char*>(WT) + dl * 512 + (((kk * 4 + g) ^ (dl & 7)) * 16));
#pragma unroll
    for (int m = 0; m < 4; ++m) {
      const int s = m * 16 + q;
      const bf16x8 afr = *reinterpret_cast<const bf16x8*>(
          reinterpret_cast<const char*>(PT) + s * 512 + (((kk * 4 + g) ^ (s & 7)) * 16));
      acc[m] = __builtin_amdgcn_mfma_f32_16x16x32_bf16(afr, bfr, acc[m], 0, 0, 0);
    }
  }
  u16* Mk = Mt + (size_t)k * 16384;                        // [s=64][d=256]
#pragma unroll
  for (int m = 0; m < 4; ++m)
#pragma unroll
    for (int j = 0; j < 4; ++j) {
      const int s = m * 16 + g * 4 + j;
      Mk[(size_t)s * 256 + d0 + w * 16 + q] = f2bf1(acc[m][j]);
    }
}

// ---------- k_main: out[t][k][s] = inp_row . Mt[k][s][:] + b2[k][s] ----------
// grid (64=k, 64=tb) -- k INNER so co-resident blocks write a contiguous
// output span (write locality).  4 waves; wave = 16 tokens x 64 s.
// All 16 A float4 loads per lane issued up-front into VGPRs; Mt_k (32KB)
// staged once via gload_lds with the verified swizzle.  LDS = 32KB (the
// epilogue store-bounce ALIASES the Mt region after a second barrier)
// -> 3 blocks/CU (launch_bounds min-waves=3, VGPR cap 168).
__global__ __launch_bounds__(256, 3) void k_main(const float* __restrict__ inp,
                                                 const u16* __restrict__ Mt,
                                                 const float* __restrict__ b2,
                                                 float* __restrict__ out) {
  const int k = blockIdx.x, tb = blockIdx.y;
  const int tid = threadIdx.x, lane = tid & 63, w = tid >> 6;
  const int q = lane & 15, g = lane >> 4;
  __shared__ __align__(16) unsigned char LDS[32768];
  u16* Bl = reinterpret_cast<u16*>(LDS);                   // Mt 32KB, swizzled
  float* Wb = reinterpret_cast<float*>(LDS + w * 4096);    // bounce (aliased)

  // 1) issue ALL A loads for this lane's token (tb*64 + w*16 + q)
  const float* Ak = inp + ((size_t)k * 4096 + (size_t)tb * 64 + w * 16 + q) * 256;
  float4 apre[16];
#pragma unroll
  for (int kk = 0; kk < 8; ++kk) {
    apre[2 * kk]     = *reinterpret_cast<const float4*>(Ak + kk * 32 + g * 8);
    apre[2 * kk + 1] = *reinterpret_cast<const float4*>(Ak + kk * 32 + g * 8 + 4);
  }

  // 2) stage Mt_k (32KB): gload_lds linear dest + inverse-swizzled source
  const u16* Mk = Mt + (size_t)k * 16384;
#pragma unroll
  for (int r = 0; r < 8; ++r) {
    const int qq = r * 256 + tid;
    const int s = qq >> 5, u = qq & 31;
    gload_lds16(Mk + (size_t)s * 256 + ((u ^ (s & 7)) * 8),
                (char*)Bl + r * 4096 + w * 1024);
  }
  f32x4 acc[4] = {};
  __syncthreads();                                         // Mt + A ready

  // 3) K loop: register A, swizzled LDS Mt frags, no barriers
#pragma unroll
  for (int kk = 0; kk < 8; ++kk) {
    bf16x8 mt[4];
#pragma unroll
    for (int n = 0; n < 4; ++n) {
      const int s = n * 16 + q;
      mt[n] = *reinterpret_cast<const bf16x8*>(
          (const char*)Bl + s * 512 + (((kk * 4 + g) ^ (s & 7)) * 16));
    }
    const float va[8] = {apre[2 * kk][0],     apre[2 * kk][1],
                         apre[2 * kk][2],     apre[2 * kk][3],
                         apre[2 * kk + 1][0], apre[2 * kk + 1][1],
                         apre[2 * kk + 1][2], apre[2 * kk + 1][3]};
    const bf16x8 a = pack8(va);
#pragma unroll
    for (int n = 0; n < 4; ++n)              // D: row=s, col=token
      acc[n] = __builtin_amdgcn_mfma_f32_16x16x32_bf16(mt[n], a, acc[n], 0, 0, 0);
  }
  __syncthreads();                           // Mt dead -> LDS reusable

  // 4) epilogue: +b2, swizzled LDS bounce, 256B-contiguous stores
  const float* b2k = b2 + k * 64;
#pragma unroll
  for (int n = 0; n < 4; ++n) {
    const float4 bv = *reinterpret_cast<const float4*>(b2k + n * 16 + g * 4);
    f32x4 r;
    r[0] = acc[n][0] + bv.x;
    r[1] = acc[n][1] + bv.y;
    r[2] = acc[n][2] + bv.z;
    r[3] = acc[n][3] + bv.w;
    const int ch = n * 4 + g;                // 16B s-chunk within token row
    *reinterpret_cast<f32x4*>(Wb + q * 64 + ((ch ^ q) * 4)) = r;
  }
#pragma unroll
  for (int j = 0; j < 4; ++j) {
    const int tq = j * 4 + g;                // local token
    const f32x4 v = *reinterpret_cast<const f32x4*>(Wb + tq * 64 + ((q ^ tq) * 4));
    const int t = tb * 64 + w * 16 + tq;
    *reinterpret_cast<f32x4*>(out + (size_t)t * 4096 + k * 64 + q * 4) = v;
  }
}

extern "C" void kernel_launch(void* const* d_in, const int* in_sizes, int n_in,
                              void* d_out, int out_size, void* d_ws, size_t ws_size,
                              hipStream_t stream) {
  const float* inp  = (const float*)d_in[0];
  // d_in[1] = fwd_expert_count (all 4096), d_in[5] = max_tokens: unused
  const float* W    = (const float*)d_in[2];
  const float* bias = (const float*)d_in[3];
  const float* P    = (const float*)d_in[4];   // [64,256,64]

  // ws: Mt bf16 [64][64][256] @0 (2 MB); b2 f32 [64][64] @2MB (16 KB)
  u16*   Mm = (u16*)d_ws;
  float* b2 = (float*)((char*)d_ws + 2097152);
  float* o  = (float*)d_out;

  k_m   <<<dim3(5, 64),  256, 0, stream>>>(P, W, bias, Mm, b2);
  k_main<<<dim3(64, 64), 256, 0, stream>>>(inp, Mm, b2, o);
}